// Round 2
// baseline (2944.756 us; speedup 1.0000x reference)
//
#include <hip/hip_runtime.h>

#define BB 128
#define TT 2048
#define DD 64
#define HH 128
#define OO 32
#define NB 16
#define SCALE 2.885390081777927f   // 2/ln2 folded into weights: tanh = 1-2*rcp(1+exp2(z))

typedef _Float16 f16x8 __attribute__((ext_vector_type(8)));
typedef __fp16   pk16x2 __attribute__((ext_vector_type(2)));
typedef float    f32x4 __attribute__((ext_vector_type(4)));

#define MFMA16(a,b,c) __builtin_amdgcn_mfma_f32_16x16x32_f16((a),(b),(c),0,0,0)

__device__ __forceinline__ f32x4 load4(const float* p){ return *(const f32x4*)p; }

// A-fragment for 16x16x32 (A[m=lane&15][k=(lane>>4)*8+j]), scaled on load.
__device__ __forceinline__ f16x8 afrag_s(const float* p, float s){
    float4 a = *(const float4*)p, b = *(const float4*)(p+4);
    f16x8 r;
    r[0]=(_Float16)(a.x*s); r[1]=(_Float16)(a.y*s); r[2]=(_Float16)(a.z*s); r[3]=(_Float16)(a.w*s);
    r[4]=(_Float16)(b.x*s); r[5]=(_Float16)(b.y*s); r[6]=(_Float16)(b.z*s); r[7]=(_Float16)(b.w*s);
    return r;
}

// tanh with z = SCALE*u pre-folded: e = 2^z = e^{2u}; tanh = 1 - 2/(1+e).
__device__ __forceinline__ float tanh_pre(float z){
#if __has_builtin(__builtin_amdgcn_exp2f)
    float e = __builtin_amdgcn_exp2f(z);
#else
    float e = exp2f(z);
#endif
    return __builtin_fmaf(-2.f, __builtin_amdgcn_rcpf(1.f + e), 1.f);
}

__device__ __forceinline__ unsigned pk2(float a, float b){
    union { pk16x2 h; unsigned u; } c;
    c.h = __builtin_amdgcn_cvt_pkrtz(a, b);
    return c.u;
}

// ---------------------------------------------------------------------------
// proj: xp0[bt][i] = SCALE * (W_ih0[i,:].x[bt,:] + b_ih0[i] + b_hh0[i]), fp16.
// ---------------------------------------------------------------------------
#define XSTR 72
extern "C" __global__ void __launch_bounds__(256)
proj_kernel(const float* __restrict__ x, const float* __restrict__ W_ih0,
            const float* __restrict__ b_ih0, const float* __restrict__ b_hh0,
            _Float16* __restrict__ xp0)
{
    const int tid = threadIdx.x;
    const int w = tid >> 6, lane = tid & 63;
    const int n = lane & 15, q = lane >> 4;
    const size_t row0 = (size_t)blockIdx.x * 64;

    __shared__ __align__(16) _Float16 XT[64][XSTR];

    #pragma unroll
    for (int it = 0; it < 4; ++it){
        float4 v = *(const float4*)(x + row0*DD + it*1024 + tid*4);
        int rr = it*16 + (tid >> 4), d0 = (tid & 15)*4;
        union { uint2 u; _Float16 h[4]; } c;
        c.h[0]=(_Float16)v.x; c.h[1]=(_Float16)v.y; c.h[2]=(_Float16)v.z; c.h[3]=(_Float16)v.w;
        *(uint2*)&XT[rr][d0] = c.u;
    }

    f16x8 A[8][2]; f32x4 bv[8];
    #pragma unroll
    for (int mt = 0; mt < 8; ++mt){
        #pragma unroll
        for (int kt = 0; kt < 2; ++kt)
            A[mt][kt] = afrag_s(W_ih0 + (mt*16 + n)*DD + kt*32 + q*8, SCALE);
        bv[mt] = (load4(b_ih0 + mt*16 + q*4) + load4(b_hh0 + mt*16 + q*4)) * SCALE;
    }
    __syncthreads();

    const _Float16* xr = &XT[w*16 + n][0];
    f16x8 B0 = *(const f16x8*)(xr + q*8);
    f16x8 B1 = *(const f16x8*)(xr + 32 + q*8);

    _Float16* orow = xp0 + (row0 + w*16 + n)*HH + q*4;
    #pragma unroll
    for (int mt = 0; mt < 8; ++mt){
        f32x4 acc = bv[mt];
        acc = MFMA16(A[mt][0], B0, acc);
        acc = MFMA16(A[mt][1], B1, acc);
        union { uint2 u; _Float16 h[4]; } s;
        #pragma unroll
        for (int r = 0; r < 4; ++r) s.h[r] = (_Float16)acc[r];
        *(uint2*)(orow + mt*16) = s.u;
    }
}

// ---------------------------------------------------------------------------
// fill: out[b][t][:] = b_fc for t >= lengths[b].
// ---------------------------------------------------------------------------
extern "C" __global__ void __launch_bounds__(256)
fill_kernel(const int* __restrict__ lengths, const float* __restrict__ b_fc,
            float* __restrict__ out)
{
    size_t idx = (size_t)blockIdx.x*256 + threadIdx.x;
    #pragma unroll
    for (int k = 0; k < 4; ++k, idx += (size_t)2048*256){
        int o4 = (int)(idx & 7);
        int t  = (int)((idx >> 3) & 2047);
        int b  = (int)(idx >> 14);
        if (t >= lengths[b])
            ((float4*)out)[idx] = *(const float4*)(b_fc + o4*4);
    }
}

// ---------------------------------------------------------------------------
// scan v3: per-layer recurrence ownership.
//   wave 0 (A): full layer-1 recurrence in one wave (32 MFMA + 32 tanh/step),
//               publishes h1[t] B-fragments into an 8-slot LDS ring.
//   wave 1 (B): full layer-2 (+FC) recurrence (72+8 MFMA + 32 tanh/step),
//               consumes h1 ring one window behind; h2 is private ping-pong.
// Block barrier only every KWIN=4 steps (ring depth 2*KWIN). All state reads
// are swizzled ds_read_b128 (stride 256B, byte ^= (n&7)<<4) -> conflict-free.
// ---------------------------------------------------------------------------
#define SLOT  (NB*256)      // 4096 B per ring slot
#define RING  8
#define KWIN  4

#define STEPA(T_, XS_) do {                                                   \
    const int t_ = (T_);                                                      \
    f32x4 z[8];                                                               \
    _Pragma("unroll")                                                         \
    for (int mt = 0; mt < 8; ++mt){                                           \
        union { uint2 u; _Float16 h[4]; } c; c.u = XS_[mt];                   \
        _Pragma("unroll")                                                     \
        for (int r = 0; r < 4; ++r) z[mt][r] = (float)c.h[r];                 \
    }                                                                         \
    _Pragma("unroll")                                                         \
    for (int kt = 0; kt < 4; ++kt)                                            \
        _Pragma("unroll")                                                     \
        for (int mt = 0; mt < 8; ++mt)                                        \
            z[mt] = MFMA16(A0[mt][kt], Wst[kt], z[mt]);                       \
    {   const int tl = (t_ + 2 < TT) ? (t_ + 2) : (TT - 1);                   \
        const char* xq = xpb + (size_t)tl*256;                                \
        _Pragma("unroll")                                                     \
        for (int mt = 0; mt < 8; ++mt) XS_[mt] = *(const uint2*)(xq + mt*32); \
    }                                                                         \
    {   char* wp = h1p + ((t_ & 7) * SLOT);                                   \
        _Pragma("unroll")                                                     \
        for (int mt = 0; mt < 8; ++mt){                                       \
            uint2 v;                                                          \
            v.x = pk2(tanh_pre(z[mt][0]), tanh_pre(z[mt][1]));                \
            v.y = pk2(tanh_pre(z[mt][2]), tanh_pre(z[mt][3]));                \
            *(uint2*)(wp + woff[mt]) = v;                                     \
        }                                                                     \
        _Pragma("unroll")                                                     \
        for (int kt = 0; kt < 4; ++kt)                                        \
            Wst[kt] = *(const f16x8*)((const char*)wp + roff[kt]);            \
    }                                                                         \
} while (0)

#define STEPB(T_) do {                                                        \
    const int t_ = (T_);                                                      \
    f16x8 bh1[4], bh2[4];                                                     \
    {   const char* rp1 = h1p + ((t_ & 7) * SLOT);                            \
        const char* rp2 = h2p + ((~t_ & 1) * SLOT);                           \
        _Pragma("unroll")                                                     \
        for (int kt = 0; kt < 4; ++kt){                                       \
            bh1[kt] = *(const f16x8*)(rp1 + roff[kt]);                        \
            bh2[kt] = *(const f16x8*)(rp2 + roff[kt]);                        \
        } }                                                                   \
    f32x4 z[8];                                                               \
    _Pragma("unroll")                                                         \
    for (int mt = 0; mt < 8; ++mt) z[mt] = b1v[mt];                           \
    _Pragma("unroll")                                                         \
    for (int kt = 0; kt < 4; ++kt)                                            \
        _Pragma("unroll")                                                     \
        for (int mt = 0; mt < 8; ++mt)                                        \
            z[mt] = MFMA16(Ai[mt][kt], bh1[kt], z[mt]);                       \
    _Pragma("unroll")                                                         \
    for (int kt = 0; kt < 4; ++kt)                                            \
        _Pragma("unroll")                                                     \
        for (int mt = 0; mt < 8; ++mt)                                        \
            z[mt] = MFMA16(Ah[mt][kt], bh2[kt], z[mt]);                       \
    {   f32x4 zf0 = bfv0, zf1 = bfv1;                                         \
        _Pragma("unroll")                                                     \
        for (int kt = 0; kt < 4; ++kt){                                       \
            zf0 = MFMA16(Af[0][kt], bh2[kt], zf0);                            \
            zf1 = MFMA16(Af[1][kt], bh2[kt], zf1);                            \
        }                                                                     \
        if ((unsigned)(t_ - 1) < (unsigned)lenn){                             \
            float* op = obase + (size_t)(t_ - 1) * OO;                        \
            float4 s0; s0.x=zf0[0]; s0.y=zf0[1]; s0.z=zf0[2]; s0.w=zf0[3];    \
            float4 s1; s1.x=zf1[0]; s1.y=zf1[1]; s1.z=zf1[2]; s1.w=zf1[3];    \
            *(float4*)op = s0; *(float4*)(op + 16) = s1;                      \
        } }                                                                   \
    {   char* wp = h2p + ((t_ & 1) * SLOT);                                   \
        _Pragma("unroll")                                                     \
        for (int mt = 0; mt < 8; ++mt){                                       \
            uint2 v;                                                          \
            v.x = pk2(tanh_pre(z[mt][0]), tanh_pre(z[mt][1]));                \
            v.y = pk2(tanh_pre(z[mt][2]), tanh_pre(z[mt][3]));                \
            *(uint2*)(wp + woff[mt]) = v;                                     \
        } }                                                                   \
} while (0)

extern "C" __global__ void __launch_bounds__(128, 1)
scan_kernel(const _Float16* __restrict__ xp0, const int* __restrict__ lengths,
            const float* __restrict__ W_hh0,
            const float* __restrict__ W_ih1, const float* __restrict__ W_hh1,
            const float* __restrict__ b_ih1, const float* __restrict__ b_hh1,
            const float* __restrict__ W_fc,  const float* __restrict__ b_fc,
            float* __restrict__ out)
{
    const int tid  = threadIdx.x;
    const int w    = tid >> 6, lane = tid & 63;
    const int n    = lane & 15, q = lane >> 4;
    const int rbase= blockIdx.x * NB;

    __shared__ __align__(16) char H1R[RING * SLOT];   // 32 KiB h1 ring
    __shared__ __align__(16) char H2P[2 * SLOT];      //  8 KiB h2 ping-pong

    for (int idx = tid; idx < (RING + 2) * SLOT / 4; idx += 128){
        if (idx < RING * SLOT / 4) ((unsigned*)H1R)[idx] = 0u;
        else ((unsigned*)H2P)[idx - RING * SLOT / 4] = 0u;
    }

    const int lenn = lengths[rbase + n];
    int mx = lenn;
    #pragma unroll
    for (int s = 1; s < 16; s <<= 1){ int o = __shfl_xor(mx, s, 64); mx = max(mx, o); }
    const int maxlen = __builtin_amdgcn_readfirstlane(mx);
    const int nwin   = (maxlen + KWIN - 1) / KWIN;
    const int W      = nwin + 1;

    // swizzled per-lane LDS offsets (row n, stride 256B, byte ^= (n&7)<<4)
    const int swz = (n & 7) << 4;
    int woff[8], roff[4];
    #pragma unroll
    for (int mt = 0; mt < 8; ++mt) woff[mt] = (mt*32 + q*8)  ^ swz;
    #pragma unroll
    for (int kt = 0; kt < 4; ++kt) roff[kt] = (kt*64 + q*16) ^ swz;
    char* h1p = H1R + n*256;
    char* h2p = H2P + n*256;

    __syncthreads();

    if (w == 0){
        // ---------------- wave A: layer-1 recurrence ----------------
        f16x8 A0[8][4];
        #pragma unroll
        for (int mt = 0; mt < 8; ++mt)
            #pragma unroll
            for (int kt = 0; kt < 4; ++kt)
                A0[mt][kt] = afrag_s(W_hh0 + (mt*16 + n)*HH + kt*32 + q*8, SCALE);

        const char* xpb = (const char*)xp0 + (size_t)(rbase + n)*TT*256 + q*8;

        f16x8 Wst[4];
        #pragma unroll
        for (int kt = 0; kt < 4; ++kt)
            #pragma unroll
            for (int j = 0; j < 8; ++j) Wst[kt][j] = (_Float16)0.f;

        uint2 XE[8], XO[8];
        #pragma unroll
        for (int mt = 0; mt < 8; ++mt){
            XE[mt] = *(const uint2*)(xpb + mt*32);
            XO[mt] = *(const uint2*)(xpb + 256 + mt*32);
        }

        for (int win = 0; win < W; ++win){
            if (win < nwin){
                const int t0 = win * KWIN;
                STEPA(t0 + 0, XE);
                STEPA(t0 + 1, XO);
                STEPA(t0 + 2, XE);
                STEPA(t0 + 3, XO);
            }
            asm volatile("s_waitcnt lgkmcnt(0)\n\ts_barrier" ::: "memory");
        }
    } else {
        // ---------------- wave B: layer-2 + FC ----------------
        f16x8 Ai[8][4], Ah[8][4], Af[2][4];
        f32x4 b1v[8];
        #pragma unroll
        for (int mt = 0; mt < 8; ++mt){
            #pragma unroll
            for (int kt = 0; kt < 4; ++kt){
                Ai[mt][kt] = afrag_s(W_ih1 + (mt*16 + n)*HH + kt*32 + q*8, SCALE);
                Ah[mt][kt] = afrag_s(W_hh1 + (mt*16 + n)*HH + kt*32 + q*8, SCALE);
            }
            b1v[mt] = (load4(b_ih1 + mt*16 + q*4)
                     + load4(b_hh1 + mt*16 + q*4)) * SCALE;
        }
        #pragma unroll
        for (int f = 0; f < 2; ++f)
            #pragma unroll
            for (int kt = 0; kt < 4; ++kt)
                Af[f][kt] = afrag_s(W_fc + (f*16 + n)*HH + kt*32 + q*8, 1.0f);
        const f32x4 bfv0 = load4(b_fc + q*4);
        const f32x4 bfv1 = load4(b_fc + 16 + q*4);

        float* obase = out + (size_t)(rbase + n)*TT*OO + q*4;

        for (int win = 0; win < W; ++win){
            if (win > 0){
                const int t0 = (win - 1) * KWIN;
                STEPB(t0 + 0);
                STEPB(t0 + 1);
                STEPB(t0 + 2);
                STEPB(t0 + 3);
            }
            asm volatile("s_waitcnt lgkmcnt(0)\n\ts_barrier" ::: "memory");
        }

        // epilogue: FC for t' = nwin*KWIN - 1 (last h2, written by this wave)
        {
            const int tl = nwin * KWIN - 1;
            const char* rp2 = h2p + ((tl & 1) * SLOT);
            f16x8 bh2[4];
            #pragma unroll
            for (int kt = 0; kt < 4; ++kt)
                bh2[kt] = *(const f16x8*)(rp2 + roff[kt]);
            f32x4 zf0 = bfv0, zf1 = bfv1;
            #pragma unroll
            for (int kt = 0; kt < 4; ++kt){
                zf0 = MFMA16(Af[0][kt], bh2[kt], zf0);
                zf1 = MFMA16(Af[1][kt], bh2[kt], zf1);
            }
            if (tl < lenn){
                float* op = obase + (size_t)tl * OO;
                float4 s0; s0.x=zf0[0]; s0.y=zf0[1]; s0.z=zf0[2]; s0.w=zf0[3];
                float4 s1; s1.x=zf1[0]; s1.y=zf1[1]; s1.z=zf1[2]; s1.w=zf1[3];
                *(float4*)op = s0; *(float4*)(op + 16) = s1;
            }
        }
    }
}

// ---------------------------------------------------------------------------
extern "C" void kernel_launch(void* const* d_in, const int* in_sizes, int n_in,
                              void* d_out, int out_size, void* d_ws, size_t ws_size,
                              hipStream_t stream)
{
    const float* x       = (const float*)d_in[0];
    const int*   lengths = (const int*)  d_in[1];
    const float* W_ih0   = (const float*)d_in[2];
    const float* W_hh0   = (const float*)d_in[3];
    const float* b_ih0   = (const float*)d_in[4];
    const float* b_hh0   = (const float*)d_in[5];
    const float* W_ih1   = (const float*)d_in[6];
    const float* W_hh1   = (const float*)d_in[7];
    const float* b_ih1   = (const float*)d_in[8];
    const float* b_hh1   = (const float*)d_in[9];
    const float* W_fc    = (const float*)d_in[10];
    const float* b_fc    = (const float*)d_in[11];

    _Float16* xp = (_Float16*)d_ws;   // [B*T][128] fp16 = 64 MiB (pre-scaled)

    proj_kernel<<<BB*TT/64, 256, 0, stream>>>(x, W_ih0, b_ih0, b_hh0, xp);
    fill_kernel<<<2048, 256, 0, stream>>>(lengths, b_fc, (float*)d_out);
    scan_kernel<<<BB/NB, 128, 0, stream>>>(xp, lengths, W_hh0,
                                           W_ih1, W_hh1, b_ih1, b_hh1,
                                           W_fc, b_fc, (float*)d_out);
}

// Round 3
// 1804.939 us; speedup vs baseline: 1.6315x; 1.6315x over previous
//
#include <hip/hip_runtime.h>

#define BB 128
#define TT 2048
#define DD 64
#define HH 128
#define OO 32
#define NB 16
#define SCALE 2.885390081777927f   // 2/ln2 folded into weights: tanh = 1-2*rcp(1+exp2(z))

typedef _Float16 f16x8 __attribute__((ext_vector_type(8)));
typedef __fp16   pk16x2 __attribute__((ext_vector_type(2)));
typedef float    f32x4 __attribute__((ext_vector_type(4)));

#define MFMA16(a,b,c) __builtin_amdgcn_mfma_f32_16x16x32_f16((a),(b),(c),0,0,0)

__device__ __forceinline__ f32x4 load4(const float* p){ return *(const f32x4*)p; }

union U8 { uint2 u[2]; f16x8 v; };

// A-fragment for 16x16x32 (A[m=lane&15][k=(lane>>4)*8+j]), scaled on load.
__device__ __forceinline__ f16x8 afrag_s(const float* p, float s){
    float4 a = *(const float4*)p, b = *(const float4*)(p+4);
    f16x8 r;
    r[0]=(_Float16)(a.x*s); r[1]=(_Float16)(a.y*s); r[2]=(_Float16)(a.z*s); r[3]=(_Float16)(a.w*s);
    r[4]=(_Float16)(b.x*s); r[5]=(_Float16)(b.y*s); r[6]=(_Float16)(b.z*s); r[7]=(_Float16)(b.w*s);
    return r;
}

// tanh with z = SCALE*u pre-folded: e = 2^z = e^{2u}; tanh = 1 - 2/(1+e).
__device__ __forceinline__ float tanh_pre(float z){
#if __has_builtin(__builtin_amdgcn_exp2f)
    float e = __builtin_amdgcn_exp2f(z);
#else
    float e = exp2f(z);
#endif
    return __builtin_fmaf(-2.f, __builtin_amdgcn_rcpf(1.f + e), 1.f);
}

__device__ __forceinline__ unsigned pk2(float a, float b){
    union { pk16x2 h; unsigned u; } c;
    c.h = __builtin_amdgcn_cvt_pkrtz(a, b);
    return c.u;
}

// ---------------------------------------------------------------------------
// proj: xp0[bt][i] = SCALE * (W_ih0[i,:].x[bt,:] + b_ih0[i] + b_hh0[i]), fp16.
// ---------------------------------------------------------------------------
#define XSTR 72
extern "C" __global__ void __launch_bounds__(256)
proj_kernel(const float* __restrict__ x, const float* __restrict__ W_ih0,
            const float* __restrict__ b_ih0, const float* __restrict__ b_hh0,
            _Float16* __restrict__ xp0)
{
    const int tid = threadIdx.x;
    const int w = tid >> 6, lane = tid & 63;
    const int n = lane & 15, q = lane >> 4;
    const size_t row0 = (size_t)blockIdx.x * 64;

    __shared__ __align__(16) _Float16 XT[64][XSTR];

    #pragma unroll
    for (int it = 0; it < 4; ++it){
        float4 v = *(const float4*)(x + row0*DD + it*1024 + tid*4);
        int rr = it*16 + (tid >> 4), d0 = (tid & 15)*4;
        union { uint2 u; _Float16 h[4]; } c;
        c.h[0]=(_Float16)v.x; c.h[1]=(_Float16)v.y; c.h[2]=(_Float16)v.z; c.h[3]=(_Float16)v.w;
        *(uint2*)&XT[rr][d0] = c.u;
    }

    f16x8 A[8][2]; f32x4 bv[8];
    #pragma unroll
    for (int mt = 0; mt < 8; ++mt){
        #pragma unroll
        for (int kt = 0; kt < 2; ++kt)
            A[mt][kt] = afrag_s(W_ih0 + (mt*16 + n)*DD + kt*32 + q*8, SCALE);
        bv[mt] = (load4(b_ih0 + mt*16 + q*4) + load4(b_hh0 + mt*16 + q*4)) * SCALE;
    }
    __syncthreads();

    const _Float16* xr = &XT[w*16 + n][0];
    f16x8 B0 = *(const f16x8*)(xr + q*8);
    f16x8 B1 = *(const f16x8*)(xr + 32 + q*8);

    _Float16* orow = xp0 + (row0 + w*16 + n)*HH + q*4;
    #pragma unroll
    for (int mt = 0; mt < 8; ++mt){
        f32x4 acc = bv[mt];
        acc = MFMA16(A[mt][0], B0, acc);
        acc = MFMA16(A[mt][1], B1, acc);
        union { uint2 u; _Float16 h[4]; } s;
        #pragma unroll
        for (int r = 0; r < 4; ++r) s.h[r] = (_Float16)acc[r];
        *(uint2*)(orow + mt*16) = s.u;
    }
}

// ---------------------------------------------------------------------------
// fill: out[b][t][:] = b_fc for t >= lengths[b].
// ---------------------------------------------------------------------------
extern "C" __global__ void __launch_bounds__(256)
fill_kernel(const int* __restrict__ lengths, const float* __restrict__ b_fc,
            float* __restrict__ out)
{
    size_t idx = (size_t)blockIdx.x*256 + threadIdx.x;
    #pragma unroll
    for (int k = 0; k < 4; ++k, idx += (size_t)2048*256){
        int o4 = (int)(idx & 7);
        int t  = (int)((idx >> 3) & 2047);
        int b  = (int)(idx >> 14);
        if (t >= lengths[b])
            ((float4*)out)[idx] = *(const float4*)(b_fc + o4*4);
    }
}

// ---------------------------------------------------------------------------
// scan v4: R1 (v2) structure with
//   (1) FC moved to the light L1 waves (w0/w1), bh2 read mid-step so the
//       post-barrier LDS burst stays at 48 b64;
//   (2) tanh+writes merged into the same basic block as the recurrence MFMAs
//       so the scheduler can overlap trans ops with MFMA issue.
// Layout identical to R1: 264B row stride, uint2 reads, 0 bank conflicts.
// ---------------------------------------------------------------------------
#define LSTR2 132               // halves per row; 264 B row stride
#define PHB   (NB*LSTR2*2)      // bytes per phase = 4224

#define STEP_L1FC(T_, P_, XS_) do {                                           \
    const int t_ = (T_);                                                      \
    U8 bh1[4];                                                                \
    _Pragma("unroll")                                                         \
    for (int kt = 0; kt < 4; ++kt){                                           \
        bh1[kt].u[0] = *(const uint2*)(h1b + (P_)*PHB + kt*64);               \
        bh1[kt].u[1] = *(const uint2*)(h1b + (P_)*PHB + kt*64 + 8);           \
    }                                                                         \
    const bool doZ0 = (t_ < maxlen);                                          \
    if (doZ0){                                                                \
        f32x4 z[4];                                                           \
        _Pragma("unroll")                                                     \
        for (int m = 0; m < 4; ++m){                                          \
            union { uint2 u; _Float16 h[4]; } c; c.u = XS_[m];                \
            _Pragma("unroll")                                                 \
            for (int r = 0; r < 4; ++r) z[m][r] = (float)c.h[r];              \
        }                                                                     \
        _Pragma("unroll")                                                     \
        for (int kt = 0; kt < 4; ++kt)                                        \
            _Pragma("unroll")                                                 \
            for (int m = 0; m < 4; ++m)                                       \
                z[m] = MFMA16(A0[m][kt], bh1[kt].v, z[m]);                    \
        _Pragma("unroll")                                                     \
        for (int m = 0; m < 4; ++m){                                          \
            uint2 v;                                                          \
            v.x = pk2(tanh_pre(z[m][0]), tanh_pre(z[m][1]));                  \
            v.y = pk2(tanh_pre(z[m][2]), tanh_pre(z[m][3]));                  \
            *(uint2*)((char*)H1T + ((P_)^1)*PHB + n*264 + (w*4+m)*32 + q*8) = v; \
        }                                                                     \
    }                                                                         \
    {   /* unconditional clamped xp reload into the SAME named slots */       \
        const int tl = (t_ + 2 < TT) ? (t_ + 2) : (TT - 1);                   \
        _Pragma("unroll")                                                     \
        for (int m = 0; m < 4; ++m)                                           \
            XS_[m] = *(const uint2*)(xpb + (size_t)tl*256 + m*32);            \
    }                                                                         \
    if (t_ >= 2){   /* FC from h2(t-2), bh2 read mid-step (buffer P stable) */\
        U8 bh2[4];                                                            \
        _Pragma("unroll")                                                     \
        for (int kt = 0; kt < 4; ++kt){                                       \
            bh2[kt].u[0] = *(const uint2*)(h2b + (P_)*PHB + kt*64);           \
            bh2[kt].u[1] = *(const uint2*)(h2b + (P_)*PHB + kt*64 + 8);       \
        }                                                                     \
        f32x4 zf = bfv;                                                       \
        _Pragma("unroll")                                                     \
        for (int kt = 0; kt < 4; ++kt) zf = MFMA16(Af[kt], bh2[kt].v, zf);    \
        if (t_ - 2 < lenn){                                                   \
            float4 sv; sv.x=zf[0]; sv.y=zf[1]; sv.z=zf[2]; sv.w=zf[3];        \
            *(float4*)(obase + (size_t)(t_-2)*OO) = sv;                       \
        }                                                                     \
    }                                                                         \
    asm volatile("s_waitcnt lgkmcnt(0)\n\ts_barrier" ::: "memory");           \
} while (0)

#define STEP_L2(T_, P_) do {                                                  \
    const int t_ = (T_);                                                      \
    U8 bh1[4], bh2[4];                                                        \
    _Pragma("unroll")                                                         \
    for (int kt = 0; kt < 4; ++kt){                                           \
        bh1[kt].u[0] = *(const uint2*)(h1b + (P_)*PHB + kt*64);               \
        bh1[kt].u[1] = *(const uint2*)(h1b + (P_)*PHB + kt*64 + 8);           \
        bh2[kt].u[0] = *(const uint2*)(h2b + (P_)*PHB + kt*64);               \
        bh2[kt].u[1] = *(const uint2*)(h2b + (P_)*PHB + kt*64 + 8);           \
    }                                                                         \
    const bool doZ1 = (t_ >= 1) && (t_ <= maxlen);                            \
    if (doZ1){                                                                \
        f32x4 z[4], y[4];                                                     \
        _Pragma("unroll")                                                     \
        for (int m = 0; m < 4; ++m){                                          \
            z[m] = b1v[m];                                                    \
            y[m][0]=0.f; y[m][1]=0.f; y[m][2]=0.f; y[m][3]=0.f;               \
        }                                                                     \
        _Pragma("unroll")                                                     \
        for (int kt = 0; kt < 4; ++kt)                                        \
            _Pragma("unroll")                                                 \
            for (int m = 0; m < 4; ++m){                                      \
                z[m] = MFMA16(Ai[m][kt], bh1[kt].v, z[m]);                    \
                y[m] = MFMA16(Ah[m][kt], bh2[kt].v, y[m]);                    \
            }                                                                 \
        _Pragma("unroll")                                                     \
        for (int m = 0; m < 4; ++m){                                          \
            z[m] += y[m];                                                     \
            uint2 v;                                                          \
            v.x = pk2(tanh_pre(z[m][0]), tanh_pre(z[m][1]));                  \
            v.y = pk2(tanh_pre(z[m][2]), tanh_pre(z[m][3]));                  \
            *(uint2*)((char*)H2T + ((P_)^1)*PHB + n*264 + (wl*4+m)*32 + q*8) = v; \
        }                                                                     \
    }                                                                         \
    asm volatile("s_waitcnt lgkmcnt(0)\n\ts_barrier" ::: "memory");           \
} while (0)

extern "C" __global__ void __launch_bounds__(256, 1)
scan_kernel(const _Float16* __restrict__ xp0, const int* __restrict__ lengths,
            const float* __restrict__ W_hh0,
            const float* __restrict__ W_ih1, const float* __restrict__ W_hh1,
            const float* __restrict__ b_ih1, const float* __restrict__ b_hh1,
            const float* __restrict__ W_fc,  const float* __restrict__ b_fc,
            float* __restrict__ out)
{
    const int tid  = threadIdx.x;
    const int w    = tid >> 6, lane = tid & 63;
    const int n    = lane & 15, q = lane >> 4;
    const int rbase= blockIdx.x * NB;

    __shared__ __align__(16) _Float16 H1T[2][NB][LSTR2];
    __shared__ __align__(16) _Float16 H2T[2][NB][LSTR2];

    for (int idx = tid; idx < (2*NB*LSTR2)/2; idx += 256){
        ((unsigned*)H1T)[idx] = 0u;
        ((unsigned*)H2T)[idx] = 0u;
    }

    const int lenn = lengths[rbase + n];
    int mx = lenn;
    #pragma unroll
    for (int s = 1; s < 16; s <<= 1){ int o = __shfl_xor(mx, s, 64); mx = max(mx, o); }
    const int maxlen = __builtin_amdgcn_readfirstlane(mx);

    const char* h1b = (const char*)H1T + n*264 + q*16;
    const char* h2b = (const char*)H2T + n*264 + q*16;

    __syncthreads();

    if (w < 2){
        // ---- L1 + FC waves: layer-1 m-tiles w*4..w*4+3, FC half f=w ----
        f16x8 A0[4][4];
        #pragma unroll
        for (int m = 0; m < 4; ++m){
            const int row = (w*4 + m)*16 + n;
            #pragma unroll
            for (int kt = 0; kt < 4; ++kt)
                A0[m][kt] = afrag_s(W_hh0 + row*HH + kt*32 + q*8, SCALE);
        }
        f16x8 Af[4];
        #pragma unroll
        for (int kt = 0; kt < 4; ++kt)
            Af[kt] = afrag_s(W_fc + (w*16 + n)*HH + kt*32 + q*8, 1.0f);
        const f32x4 bfv = load4(b_fc + w*16 + q*4);

        const char* xpb = (const char*)(xp0 + ((size_t)(rbase+n)*TT)*HH)
                          + (w*4)*32 + q*8;
        float* obase = out + ((size_t)(rbase+n)*TT)*OO + w*16 + q*4;

        uint2 xe[4], xo[4];
        #pragma unroll
        for (int m = 0; m < 4; ++m){
            xe[m] = *(const uint2*)(xpb + m*32);
            xo[m] = *(const uint2*)(xpb + 256 + m*32);
        }

        for (int t0 = 0; t0 <= maxlen + 1; t0 += 2){
            STEP_L1FC(t0,     0, xe);
            STEP_L1FC(t0 + 1, 1, xo);
        }
    } else {
        // ---- pure layer-2 waves: m-tiles wl*4..wl*4+3 ----
        const int wl = w - 2;
        f16x8 Ai[4][4], Ah[4][4];
        f32x4 b1v[4];
        #pragma unroll
        for (int m = 0; m < 4; ++m){
            const int row = (wl*4 + m)*16 + n;
            #pragma unroll
            for (int kt = 0; kt < 4; ++kt){
                Ai[m][kt] = afrag_s(W_ih1 + row*HH + kt*32 + q*8, SCALE);
                Ah[m][kt] = afrag_s(W_hh1 + row*HH + kt*32 + q*8, SCALE);
            }
            b1v[m] = (load4(b_ih1 + (wl*4+m)*16 + q*4)
                    + load4(b_hh1 + (wl*4+m)*16 + q*4)) * SCALE;
        }

        for (int t0 = 0; t0 <= maxlen + 1; t0 += 2){
            STEP_L2(t0,     0);
            STEP_L2(t0 + 1, 1);
        }
    }
}

// ---------------------------------------------------------------------------
extern "C" void kernel_launch(void* const* d_in, const int* in_sizes, int n_in,
                              void* d_out, int out_size, void* d_ws, size_t ws_size,
                              hipStream_t stream)
{
    const float* x       = (const float*)d_in[0];
    const int*   lengths = (const int*)  d_in[1];
    const float* W_ih0   = (const float*)d_in[2];
    const float* W_hh0   = (const float*)d_in[3];
    const float* b_ih0   = (const float*)d_in[4];
    const float* b_hh0   = (const float*)d_in[5];
    const float* W_ih1   = (const float*)d_in[6];
    const float* W_hh1   = (const float*)d_in[7];
    const float* b_ih1   = (const float*)d_in[8];
    const float* b_hh1   = (const float*)d_in[9];
    const float* W_fc    = (const float*)d_in[10];
    const float* b_fc    = (const float*)d_in[11];

    _Float16* xp = (_Float16*)d_ws;   // [B*T][128] fp16 = 64 MiB (pre-scaled)

    proj_kernel<<<BB*TT/64, 256, 0, stream>>>(x, W_ih0, b_ih0, b_hh0, xp);
    fill_kernel<<<2048, 256, 0, stream>>>(lengths, b_fc, (float*)d_out);
    scan_kernel<<<BB/NB, 256, 0, stream>>>(xp, lengths, W_hh0,
                                           W_ih1, W_hh1, b_ih1, b_hh1,
                                           W_fc, b_fc, (float*)d_out);
}

// Round 4
// 1674.401 us; speedup vs baseline: 1.7587x; 1.0780x over previous
//
#include <hip/hip_runtime.h>

#define BB 128
#define TT 2048
#define DD 64
#define HH 128
#define OO 32
#define NB 16
#define SCALE 2.885390081777927f   // 2/ln2 folded into weights: tanh = 1-2*rcp(1+exp2(z))

typedef _Float16 f16x8 __attribute__((ext_vector_type(8)));
typedef __fp16   pk16x2 __attribute__((ext_vector_type(2)));
typedef float    f32x4 __attribute__((ext_vector_type(4)));

#define MFMA16(a,b,c) __builtin_amdgcn_mfma_f32_16x16x32_f16((a),(b),(c),0,0,0)

__device__ __forceinline__ f32x4 load4(const float* p){ return *(const f32x4*)p; }

union U8 { uint2 u[2]; f16x8 v; };

// A-fragment for 16x16x32 (A[m=lane&15][k=(lane>>4)*8+j]), scaled on load.
__device__ __forceinline__ f16x8 afrag_s(const float* p, float s){
    float4 a = *(const float4*)p, b = *(const float4*)(p+4);
    f16x8 r;
    r[0]=(_Float16)(a.x*s); r[1]=(_Float16)(a.y*s); r[2]=(_Float16)(a.z*s); r[3]=(_Float16)(a.w*s);
    r[4]=(_Float16)(b.x*s); r[5]=(_Float16)(b.y*s); r[6]=(_Float16)(b.z*s); r[7]=(_Float16)(b.w*s);
    return r;
}

// tanh with z = SCALE*u pre-folded: e = 2^z = e^{2u}; tanh = 1 - 2/(1+e).
__device__ __forceinline__ float tanh_pre(float z){
#if __has_builtin(__builtin_amdgcn_exp2f)
    float e = __builtin_amdgcn_exp2f(z);
#else
    float e = exp2f(z);
#endif
    return __builtin_fmaf(-2.f, __builtin_amdgcn_rcpf(1.f + e), 1.f);
}

__device__ __forceinline__ unsigned pk2(float a, float b){
    union { pk16x2 h; unsigned u; } c;
    c.h = __builtin_amdgcn_cvt_pkrtz(a, b);
    return c.u;
}

// pack 8 f32 (two float4) into an f16x8 B-fragment (RTZ, same as h path).
__device__ __forceinline__ f16x8 xfrag(float4 a, float4 b){
    union { unsigned u[4]; f16x8 v; } c;
    c.u[0] = pk2(a.x, a.y); c.u[1] = pk2(a.z, a.w);
    c.u[2] = pk2(b.x, b.y); c.u[3] = pk2(b.z, b.w);
    return c.v;
}

// ---------------------------------------------------------------------------
// scan v5 = v2 (R1, 1441us) with proj fused into the light L1 waves and the
// pad-fill fused into a per-block tail. Single kernel does everything.
//   waves 0-1: layer-1: z0 = b0 + W_ih0*x(t) [inline proj, +8 MFMA] +
//              W_hh0*h1(t-1); 24 MFMA + 8 b64 reads + 4 global x-loads.
//   waves 2-3: layer-2 + FC (bh2 shared between y and FC): 36 MFMA + 16 b64.
// LDS: 264B row stride (0 bank conflicts), uint2 reads, dbuf by parity.
// ---------------------------------------------------------------------------
#define LSTR2 132               // halves per row; 264 B row stride
#define PHB   (NB*LSTR2*2)      // bytes per phase = 4224

#define STEP_L1(T_, P_, XS_) do {                                             \
    const int t_ = (T_);                                                      \
    U8 bh1[4];                                                                \
    _Pragma("unroll")                                                         \
    for (int kt = 0; kt < 4; ++kt){                                           \
        bh1[kt].u[0] = *(const uint2*)(h1b + (P_)*PHB + kt*64);               \
        bh1[kt].u[1] = *(const uint2*)(h1b + (P_)*PHB + kt*64 + 8);           \
    }                                                                         \
    f32x4 z[4];                                                               \
    const bool doZ0 = (t_ < maxlen);                                          \
    if (doZ0){                                                                \
        f16x8 xB0 = xfrag(XS_[0], XS_[1]);                                    \
        f16x8 xB1 = xfrag(XS_[2], XS_[3]);                                    \
        _Pragma("unroll")                                                     \
        for (int m = 0; m < 4; ++m){                                          \
            z[m] = bv0[m];                                                    \
            z[m] = MFMA16(Aih[m][0], xB0, z[m]);                              \
            z[m] = MFMA16(Aih[m][1], xB1, z[m]);                              \
        }                                                                     \
        _Pragma("unroll")                                                     \
        for (int kt = 0; kt < 4; ++kt)                                        \
            _Pragma("unroll")                                                 \
            for (int m = 0; m < 4; ++m)                                       \
                z[m] = MFMA16(A0[m][kt], bh1[kt].v, z[m]);                    \
    }                                                                         \
    {   /* unconditional clamped x reload into the SAME named slots */        \
        const int tl = (t_ + 2 < TT) ? (t_ + 2) : (TT - 1);                   \
        const float* xq = xb + (size_t)tl*DD;                                 \
        XS_[0] = *(const float4*)(xq);                                        \
        XS_[1] = *(const float4*)(xq + 4);                                    \
        XS_[2] = *(const float4*)(xq + 32);                                   \
        XS_[3] = *(const float4*)(xq + 36);                                   \
    }                                                                         \
    if (doZ0){                                                                \
        _Pragma("unroll")                                                     \
        for (int m = 0; m < 4; ++m){                                          \
            uint2 v;                                                          \
            v.x = pk2(tanh_pre(z[m][0]), tanh_pre(z[m][1]));                  \
            v.y = pk2(tanh_pre(z[m][2]), tanh_pre(z[m][3]));                  \
            *(uint2*)((char*)H1T + ((P_)^1)*PHB + n*264 + (w*4+m)*32 + q*8) = v; \
        }                                                                     \
    }                                                                         \
    asm volatile("s_waitcnt lgkmcnt(0)\n\ts_barrier" ::: "memory");           \
} while (0)

#define STEP_L2(T_, P_) do {                                                  \
    const int t_ = (T_);                                                      \
    U8 bh1[4], bh2[4];                                                        \
    _Pragma("unroll")                                                         \
    for (int kt = 0; kt < 4; ++kt){                                           \
        bh1[kt].u[0] = *(const uint2*)(h1b + (P_)*PHB + kt*64);               \
        bh1[kt].u[1] = *(const uint2*)(h1b + (P_)*PHB + kt*64 + 8);           \
        bh2[kt].u[0] = *(const uint2*)(h2b + (P_)*PHB + kt*64);               \
        bh2[kt].u[1] = *(const uint2*)(h2b + (P_)*PHB + kt*64 + 8);           \
    }                                                                         \
    const bool doZ1 = (t_ >= 1) && (t_ <= maxlen);                            \
    f32x4 z[4];                                                               \
    if (doZ1){                                                                \
        f32x4 y[4];                                                           \
        _Pragma("unroll")                                                     \
        for (int m = 0; m < 4; ++m){                                          \
            z[m] = b1v[m];                                                    \
            y[m][0]=0.f; y[m][1]=0.f; y[m][2]=0.f; y[m][3]=0.f;               \
        }                                                                     \
        _Pragma("unroll")                                                     \
        for (int kt = 0; kt < 4; ++kt)                                        \
            _Pragma("unroll")                                                 \
            for (int m = 0; m < 4; ++m){                                      \
                z[m] = MFMA16(Ai[m][kt], bh1[kt].v, z[m]);                    \
                y[m] = MFMA16(Ah[m][kt], bh2[kt].v, y[m]);                    \
            }                                                                 \
        _Pragma("unroll")                                                     \
        for (int m = 0; m < 4; ++m) z[m] += y[m];                             \
    }                                                                         \
    if (t_ >= 2){                                                             \
        f32x4 zf = bfv;                                                       \
        _Pragma("unroll")                                                     \
        for (int kt = 0; kt < 4; ++kt) zf = MFMA16(Af[kt], bh2[kt].v, zf);    \
        if (t_ - 2 < lenn){                                                   \
            float4 sv; sv.x=zf[0]; sv.y=zf[1]; sv.z=zf[2]; sv.w=zf[3];        \
            *(float4*)(obase + (size_t)(t_-2)*OO) = sv;                       \
        }                                                                     \
    }                                                                         \
    if (doZ1){                                                                \
        _Pragma("unroll")                                                     \
        for (int m = 0; m < 4; ++m){                                          \
            uint2 v;                                                          \
            v.x = pk2(tanh_pre(z[m][0]), tanh_pre(z[m][1]));                  \
            v.y = pk2(tanh_pre(z[m][2]), tanh_pre(z[m][3]));                  \
            *(uint2*)((char*)H2T + ((P_)^1)*PHB + n*264 + (wl*4+m)*32 + q*8) = v; \
        }                                                                     \
    }                                                                         \
    asm volatile("s_waitcnt lgkmcnt(0)\n\ts_barrier" ::: "memory");           \
} while (0)

extern "C" __global__ void __launch_bounds__(256, 1)
scan_kernel(const float* __restrict__ x, const int* __restrict__ lengths,
            const float* __restrict__ W_ih0, const float* __restrict__ W_hh0,
            const float* __restrict__ b_ih0, const float* __restrict__ b_hh0,
            const float* __restrict__ W_ih1, const float* __restrict__ W_hh1,
            const float* __restrict__ b_ih1, const float* __restrict__ b_hh1,
            const float* __restrict__ W_fc,  const float* __restrict__ b_fc,
            float* __restrict__ out)
{
    const int tid  = threadIdx.x;
    const int w    = tid >> 6, lane = tid & 63;
    const int n    = lane & 15, q = lane >> 4;
    const int rbase= blockIdx.x * NB;

    __shared__ __align__(16) _Float16 H1T[2][NB][LSTR2];
    __shared__ __align__(16) _Float16 H2T[2][NB][LSTR2];

    for (int idx = tid; idx < (2*NB*LSTR2)/2; idx += 256){
        ((unsigned*)H1T)[idx] = 0u;
        ((unsigned*)H2T)[idx] = 0u;
    }

    const int lenn = lengths[rbase + n];
    int mx = lenn;
    #pragma unroll
    for (int s = 1; s < 16; s <<= 1){ int o = __shfl_xor(mx, s, 64); mx = max(mx, o); }
    const int maxlen = __builtin_amdgcn_readfirstlane(mx);

    const char* h1b = (const char*)H1T + n*264 + q*16;
    const char* h2b = (const char*)H2T + n*264 + q*16;

    __syncthreads();

    if (w < 2){
        // ---- L1 waves: m-tiles w*4..w*4+3; proj fused inline ----
        f16x8 A0[4][4], Aih[4][2];
        f32x4 bv0[4];
        #pragma unroll
        for (int m = 0; m < 4; ++m){
            const int row = (w*4 + m)*16 + n;
            #pragma unroll
            for (int kt = 0; kt < 4; ++kt)
                A0[m][kt] = afrag_s(W_hh0 + row*HH + kt*32 + q*8, SCALE);
            #pragma unroll
            for (int kt = 0; kt < 2; ++kt)
                Aih[m][kt] = afrag_s(W_ih0 + row*DD + kt*32 + q*8, SCALE);
            bv0[m] = (load4(b_ih0 + (w*4+m)*16 + q*4)
                    + load4(b_hh0 + (w*4+m)*16 + q*4)) * SCALE;
        }

        const float* xb = x + ((size_t)(rbase+n)*TT)*DD + q*8;

        float4 xe[4], xo[4];
        {
            const float* x0 = xb;
            const float* x1 = xb + DD;
            xe[0] = *(const float4*)(x0);      xe[1] = *(const float4*)(x0 + 4);
            xe[2] = *(const float4*)(x0 + 32); xe[3] = *(const float4*)(x0 + 36);
            xo[0] = *(const float4*)(x1);      xo[1] = *(const float4*)(x1 + 4);
            xo[2] = *(const float4*)(x1 + 32); xo[3] = *(const float4*)(x1 + 36);
        }

        for (int t0 = 0; t0 <= maxlen + 1; t0 += 2){
            STEP_L1(t0,     0, xe);
            STEP_L1(t0 + 1, 1, xo);
        }
    } else {
        // ---- L2 + FC waves: m-tiles wl*4..wl*4+3, FC half f=w&1 ----
        const int wl = w - 2, f = w & 1;
        f16x8 Ai[4][4], Ah[4][4];
        f32x4 b1v[4];
        #pragma unroll
        for (int m = 0; m < 4; ++m){
            const int row = (wl*4 + m)*16 + n;
            #pragma unroll
            for (int kt = 0; kt < 4; ++kt){
                Ai[m][kt] = afrag_s(W_ih1 + row*HH + kt*32 + q*8, SCALE);
                Ah[m][kt] = afrag_s(W_hh1 + row*HH + kt*32 + q*8, SCALE);
            }
            b1v[m] = (load4(b_ih1 + (wl*4+m)*16 + q*4)
                    + load4(b_hh1 + (wl*4+m)*16 + q*4)) * SCALE;
        }
        f16x8 Af[4];
        #pragma unroll
        for (int kt = 0; kt < 4; ++kt)
            Af[kt] = afrag_s(W_fc + (f*16 + n)*HH + kt*32 + q*8, 1.0f);
        const f32x4 bfv = load4(b_fc + f*16 + q*4);

        float* obase = out + ((size_t)(rbase+n)*TT)*OO + f*16 + q*4;

        for (int t0 = 0; t0 <= maxlen + 1; t0 += 2){
            STEP_L2(t0,     0);
            STEP_L2(t0 + 1, 1);
        }
    }

    // ---- fused pad-fill tail: out[b][t][:] = b_fc for t >= lengths[b] ----
    {
        const int rl   = lane >> 4;            // 0..3
        const int row  = w*4 + rl;             // 0..15 across 4 waves
        const int lr   = lengths[rbase + row];
        const int o4   = lane & 7;             // float4 index within 32 floats
        const int tpar = (lane >> 3) & 1;      // t parity
        const float4 bf4 = *(const float4*)(b_fc + o4*4);
        float* ob = out + ((size_t)(rbase+row)*TT)*OO + o4*4;
        for (int t = lr + tpar; t < TT; t += 2)
            *(float4*)(ob + (size_t)t*OO) = bf4;
    }
}

// ---------------------------------------------------------------------------
extern "C" void kernel_launch(void* const* d_in, const int* in_sizes, int n_in,
                              void* d_out, int out_size, void* d_ws, size_t ws_size,
                              hipStream_t stream)
{
    const float* x       = (const float*)d_in[0];
    const int*   lengths = (const int*)  d_in[1];
    const float* W_ih0   = (const float*)d_in[2];
    const float* W_hh0   = (const float*)d_in[3];
    const float* b_ih0   = (const float*)d_in[4];
    const float* b_hh0   = (const float*)d_in[5];
    const float* W_ih1   = (const float*)d_in[6];
    const float* W_hh1   = (const float*)d_in[7];
    const float* b_ih1   = (const float*)d_in[8];
    const float* b_hh1   = (const float*)d_in[9];
    const float* W_fc    = (const float*)d_in[10];
    const float* b_fc    = (const float*)d_in[11];

    scan_kernel<<<BB/NB, 256, 0, stream>>>(x, lengths, W_ih0, W_hh0,
                                           b_ih0, b_hh0,
                                           W_ih1, W_hh1, b_ih1, b_hh1,
                                           W_fc, b_fc, (float*)d_out);
}

// Round 6
// 1592.279 us; speedup vs baseline: 1.8494x; 1.0516x over previous
//
#include <hip/hip_runtime.h>

#define BB 128
#define TT 2048
#define DD 64
#define HH 128
#define OO 32
#define NB 16
#define SCALE 2.885390081777927f   // 2/ln2 folded into weights: tanh = 1-2*rcp(1+exp2(z))

typedef _Float16 f16x8 __attribute__((ext_vector_type(8)));
typedef __fp16   pk16x2 __attribute__((ext_vector_type(2)));
typedef float    f32x4 __attribute__((ext_vector_type(4)));

#define MFMA16(a,b,c) __builtin_amdgcn_mfma_f32_16x16x32_f16((a),(b),(c),0,0,0)

__device__ __forceinline__ f32x4 load4(const float* p){ return *(const f32x4*)p; }

union U8 { uint2 u[2]; f16x8 v; };

// A-fragment for 16x16x32 (A[m=lane&15][k=(lane>>4)*8+j]), scaled on load.
__device__ __forceinline__ f16x8 afrag_s(const float* p, float s){
    float4 a = *(const float4*)p, b = *(const float4*)(p+4);
    f16x8 r;
    r[0]=(_Float16)(a.x*s); r[1]=(_Float16)(a.y*s); r[2]=(_Float16)(a.z*s); r[3]=(_Float16)(a.w*s);
    r[4]=(_Float16)(b.x*s); r[5]=(_Float16)(b.y*s); r[6]=(_Float16)(b.z*s); r[7]=(_Float16)(b.w*s);
    return r;
}

// tanh with z = SCALE*u pre-folded: e = 2^z = e^{2u}; tanh = 1 - 2/(1+e).
__device__ __forceinline__ float tanh_pre(float z){
#if __has_builtin(__builtin_amdgcn_exp2f)
    float e = __builtin_amdgcn_exp2f(z);
#else
    float e = exp2f(z);
#endif
    return __builtin_fmaf(-2.f, __builtin_amdgcn_rcpf(1.f + e), 1.f);
}

__device__ __forceinline__ unsigned pk2(float a, float b){
    union { pk16x2 h; unsigned u; } c;
    c.h = __builtin_amdgcn_cvt_pkrtz(a, b);
    return c.u;
}

// pack 8 f32 (two float4) into an f16x8 B-fragment (RTZ, same as h path).
__device__ __forceinline__ f16x8 xfrag(float4 a, float4 b){
    union { unsigned u[4]; f16x8 v; } c;
    c.u[0] = pk2(a.x, a.y); c.u[1] = pk2(a.z, a.w);
    c.u[2] = pk2(b.x, b.y); c.u[3] = pk2(b.z, b.w);
    return c.v;
}

// ---------------------------------------------------------------------------
// scan v6 = v5 algorithm with 8 waves (2 waves/SIMD) so per-SIMD issue
// serialization is hidden by the co-resident wave.
//   waves 0-3 (SIMD w):   layer-1, m-tiles {2w,2w+1}: 4 proj + 8 rec MFMA.
//   waves 4-7 (SIMD w-4): layer-2, m-tiles {2(w-4),2(w-4)+1}: 16 MFMA;
//                         waves 4,5 add FC half (w-4): +4 MFMA + store.
// LDS: 264B row stride (0 bank conflicts), uint2 reads, dbuf by parity,
// one barrier per step. Pad-fill fused as per-block tail.
// ---------------------------------------------------------------------------
#define LSTR2 132               // halves per row; 264 B row stride
#define PHB   (NB*LSTR2*2)      // bytes per phase = 4224

#define STEP_L1(T_, P_, XS_) do {                                             \
    const int t_ = (T_);                                                      \
    U8 bh1[4];                                                                \
    _Pragma("unroll")                                                         \
    for (int kt = 0; kt < 4; ++kt){                                           \
        bh1[kt].u[0] = *(const uint2*)(h1b + (P_)*PHB + kt*64);               \
        bh1[kt].u[1] = *(const uint2*)(h1b + (P_)*PHB + kt*64 + 8);           \
    }                                                                         \
    f32x4 z[2];                                                               \
    const bool doZ0 = (t_ < maxlen);                                          \
    if (doZ0){                                                                \
        f16x8 xB0 = xfrag(XS_[0], XS_[1]);                                    \
        f16x8 xB1 = xfrag(XS_[2], XS_[3]);                                    \
        _Pragma("unroll")                                                     \
        for (int m = 0; m < 2; ++m){                                          \
            z[m] = bv0[m];                                                    \
            z[m] = MFMA16(Aih[m][0], xB0, z[m]);                              \
            z[m] = MFMA16(Aih[m][1], xB1, z[m]);                              \
        }                                                                     \
        _Pragma("unroll")                                                     \
        for (int kt = 0; kt < 4; ++kt)                                        \
            _Pragma("unroll")                                                 \
            for (int m = 0; m < 2; ++m)                                       \
                z[m] = MFMA16(A0[m][kt], bh1[kt].v, z[m]);                    \
    }                                                                         \
    {   /* unconditional clamped x reload into the SAME named slots */        \
        const int tl = (t_ + 2 < TT) ? (t_ + 2) : (TT - 1);                   \
        const float* xq = xb + (size_t)tl*DD;                                 \
        XS_[0] = *(const float4*)(xq);                                        \
        XS_[1] = *(const float4*)(xq + 4);                                    \
        XS_[2] = *(const float4*)(xq + 32);                                   \
        XS_[3] = *(const float4*)(xq + 36);                                   \
    }                                                                         \
    if (doZ0){                                                                \
        _Pragma("unroll")                                                     \
        for (int m = 0; m < 2; ++m){                                          \
            uint2 v;                                                          \
            v.x = pk2(tanh_pre(z[m][0]), tanh_pre(z[m][1]));                  \
            v.y = pk2(tanh_pre(z[m][2]), tanh_pre(z[m][3]));                  \
            *(uint2*)((char*)H1T + ((P_)^1)*PHB + n*264 + (w*2+m)*32 + q*8) = v; \
        }                                                                     \
    }                                                                         \
    asm volatile("s_waitcnt lgkmcnt(0)\n\ts_barrier" ::: "memory");           \
} while (0)

#define STEP_L2(T_, P_) do {                                                  \
    const int t_ = (T_);                                                      \
    U8 bh1[4], bh2[4];                                                        \
    _Pragma("unroll")                                                         \
    for (int kt = 0; kt < 4; ++kt){                                           \
        bh1[kt].u[0] = *(const uint2*)(h1b + (P_)*PHB + kt*64);               \
        bh1[kt].u[1] = *(const uint2*)(h1b + (P_)*PHB + kt*64 + 8);           \
        bh2[kt].u[0] = *(const uint2*)(h2b + (P_)*PHB + kt*64);               \
        bh2[kt].u[1] = *(const uint2*)(h2b + (P_)*PHB + kt*64 + 8);           \
    }                                                                         \
    const bool doZ1 = (t_ >= 1) && (t_ <= maxlen);                            \
    f32x4 z[2];                                                               \
    if (doZ1){                                                                \
        f32x4 y[2];                                                           \
        _Pragma("unroll")                                                     \
        for (int m = 0; m < 2; ++m){                                          \
            z[m] = b1v[m];                                                    \
            y[m][0]=0.f; y[m][1]=0.f; y[m][2]=0.f; y[m][3]=0.f;               \
        }                                                                     \
        _Pragma("unroll")                                                     \
        for (int kt = 0; kt < 4; ++kt)                                        \
            _Pragma("unroll")                                                 \
            for (int m = 0; m < 2; ++m){                                      \
                z[m] = MFMA16(Ai[m][kt], bh1[kt].v, z[m]);                    \
                y[m] = MFMA16(Ah[m][kt], bh2[kt].v, y[m]);                    \
            }                                                                 \
        _Pragma("unroll")                                                     \
        for (int m = 0; m < 2; ++m) z[m] += y[m];                             \
    }                                                                         \
    if (doFC && t_ >= 2){                                                     \
        f32x4 zf = bfv;                                                       \
        _Pragma("unroll")                                                     \
        for (int kt = 0; kt < 4; ++kt) zf = MFMA16(Af[kt], bh2[kt].v, zf);    \
        if (t_ - 2 < lenn){                                                   \
            float4 sv; sv.x=zf[0]; sv.y=zf[1]; sv.z=zf[2]; sv.w=zf[3];        \
            *(float4*)(obase + (size_t)(t_-2)*OO) = sv;                       \
        }                                                                     \
    }                                                                         \
    if (doZ1){                                                                \
        _Pragma("unroll")                                                     \
        for (int m = 0; m < 2; ++m){                                          \
            uint2 v;                                                          \
            v.x = pk2(tanh_pre(z[m][0]), tanh_pre(z[m][1]));                  \
            v.y = pk2(tanh_pre(z[m][2]), tanh_pre(z[m][3]));                  \
            *(uint2*)((char*)H2T + ((P_)^1)*PHB + n*264 + (wl*2+m)*32 + q*8) = v; \
        }                                                                     \
    }                                                                         \
    asm volatile("s_waitcnt lgkmcnt(0)\n\ts_barrier" ::: "memory");           \
} while (0)

extern "C" __global__ void __launch_bounds__(512, 1)
scan_kernel(const float* __restrict__ x, const int* __restrict__ lengths,
            const float* __restrict__ W_ih0, const float* __restrict__ W_hh0,
            const float* __restrict__ b_ih0, const float* __restrict__ b_hh0,
            const float* __restrict__ W_ih1, const float* __restrict__ W_hh1,
            const float* __restrict__ b_ih1, const float* __restrict__ b_hh1,
            const float* __restrict__ W_fc,  const float* __restrict__ b_fc,
            float* __restrict__ out)
{
    const int tid  = threadIdx.x;
    const int w    = tid >> 6, lane = tid & 63;
    const int n    = lane & 15, q = lane >> 4;
    const int rbase= blockIdx.x * NB;

    __shared__ __align__(16) _Float16 H1T[2][NB][LSTR2];
    __shared__ __align__(16) _Float16 H2T[2][NB][LSTR2];

    for (int idx = tid; idx < (2*NB*LSTR2)/2; idx += 512){
        ((unsigned*)H1T)[idx] = 0u;
        ((unsigned*)H2T)[idx] = 0u;
    }

    const int lenn = lengths[rbase + n];
    int mx = lenn;
    #pragma unroll
    for (int s = 1; s < 16; s <<= 1){ int o = __shfl_xor(mx, s, 64); mx = max(mx, o); }
    const int maxlen = __builtin_amdgcn_readfirstlane(mx);

    const char* h1b = (const char*)H1T + n*264 + q*16;
    const char* h2b = (const char*)H2T + n*264 + q*16;

    __syncthreads();

    if (w < 4){
        // ---- L1 waves: m-tiles {2w, 2w+1}; proj fused inline ----
        f16x8 A0[2][4], Aih[2][2];
        f32x4 bv0[2];
        #pragma unroll
        for (int m = 0; m < 2; ++m){
            const int row = (w*2 + m)*16 + n;
            #pragma unroll
            for (int kt = 0; kt < 4; ++kt)
                A0[m][kt] = afrag_s(W_hh0 + row*HH + kt*32 + q*8, SCALE);
            #pragma unroll
            for (int kt = 0; kt < 2; ++kt)
                Aih[m][kt] = afrag_s(W_ih0 + row*DD + kt*32 + q*8, SCALE);
            bv0[m] = (load4(b_ih0 + (w*2+m)*16 + q*4)
                    + load4(b_hh0 + (w*2+m)*16 + q*4)) * SCALE;
        }

        const float* xb = x + ((size_t)(rbase+n)*TT)*DD + q*8;

        float4 xe[4], xo[4];
        {
            const float* x0 = xb;
            const float* x1 = xb + DD;
            xe[0] = *(const float4*)(x0);      xe[1] = *(const float4*)(x0 + 4);
            xe[2] = *(const float4*)(x0 + 32); xe[3] = *(const float4*)(x0 + 36);
            xo[0] = *(const float4*)(x1);      xo[1] = *(const float4*)(x1 + 4);
            xo[2] = *(const float4*)(x1 + 32); xo[3] = *(const float4*)(x1 + 36);
        }

        for (int t0 = 0; t0 <= maxlen + 1; t0 += 2){
            STEP_L1(t0,     0, xe);
            STEP_L1(t0 + 1, 1, xo);
        }
    } else {
        // ---- L2 waves: m-tiles {2wl, 2wl+1}; waves 4,5 add FC half wl ----
        const int wl = w - 4;
        const bool doFC = (wl < 2);
        const int f = wl & 1;
        f16x8 Ai[2][4], Ah[2][4];
        f32x4 b1v[2];
        #pragma unroll
        for (int m = 0; m < 2; ++m){
            const int row = (wl*2 + m)*16 + n;
            #pragma unroll
            for (int kt = 0; kt < 4; ++kt){
                Ai[m][kt] = afrag_s(W_ih1 + row*HH + kt*32 + q*8, SCALE);
                Ah[m][kt] = afrag_s(W_hh1 + row*HH + kt*32 + q*8, SCALE);
            }
            b1v[m] = (load4(b_ih1 + (wl*2+m)*16 + q*4)
                    + load4(b_hh1 + (wl*2+m)*16 + q*4)) * SCALE;
        }
        f16x8 Af[4];
        #pragma unroll
        for (int kt = 0; kt < 4; ++kt)
            Af[kt] = afrag_s(W_fc + (f*16 + n)*HH + kt*32 + q*8, 1.0f);
        const f32x4 bfv = load4(b_fc + f*16 + q*4);

        float* obase = out + ((size_t)(rbase+n)*TT)*OO + f*16 + q*4;

        for (int t0 = 0; t0 <= maxlen + 1; t0 += 2){
            STEP_L2(t0,     0);
            STEP_L2(t0 + 1, 1);
        }
    }

    // ---- fused pad-fill tail: out[b][t][:] = b_fc for t >= lengths[b] ----
    {
        const int row  = tid >> 5;             // 0..15
        const int lr   = lengths[rbase + row];
        const int o4   = tid & 7;              // float4 index within 32 floats
        const int tpar = (tid >> 3) & 3;       // t parity (stride 4)
        const float4 bf4 = *(const float4*)(b_fc + o4*4);
        float* ob = out + ((size_t)(rbase+row)*TT)*OO + o4*4;
        for (int t = lr + tpar; t < TT; t += 4)
            *(float4*)(ob + (size_t)t*OO) = bf4;
    }
}

// ---------------------------------------------------------------------------
extern "C" void kernel_launch(void* const* d_in, const int* in_sizes, int n_in,
                              void* d_out, int out_size, void* d_ws, size_t ws_size,
                              hipStream_t stream)
{
    const float* x       = (const float*)d_in[0];
    const int*   lengths = (const int*)  d_in[1];
    const float* W_ih0   = (const float*)d_in[2];
    const float* W_hh0   = (const float*)d_in[3];
    const float* b_ih0   = (const float*)d_in[4];
    const float* b_hh0   = (const float*)d_in[5];
    const float* W_ih1   = (const float*)d_in[6];
    const float* W_hh1   = (const float*)d_in[7];
    const float* b_ih1   = (const float*)d_in[8];
    const float* b_hh1   = (const float*)d_in[9];
    const float* W_fc    = (const float*)d_in[10];
    const float* b_fc    = (const float*)d_in[11];

    scan_kernel<<<BB/NB, 512, 0, stream>>>(x, lengths, W_ih0, W_hh0,
                                           b_ih0, b_hh0,
                                           W_ih1, W_hh1, b_ih1, b_hh1,
                                           W_fc, b_fc, (float*)d_out);
}

// Round 7
// 1584.052 us; speedup vs baseline: 1.8590x; 1.0052x over previous
//
#include <hip/hip_runtime.h>

#define BB 128
#define TT 2048
#define DD 64
#define HH 128
#define OO 32
#define NB 16
#define SCALE 2.885390081777927f   // 2/ln2 folded into weights: tanh = 1-2*rcp(1+exp2(z))

typedef _Float16 f16x8 __attribute__((ext_vector_type(8)));
typedef __fp16   pk16x2 __attribute__((ext_vector_type(2)));
typedef float    f32x4 __attribute__((ext_vector_type(4)));

#define MFMA16(a,b,c) __builtin_amdgcn_mfma_f32_16x16x32_f16((a),(b),(c),0,0,0)

__device__ __forceinline__ f32x4 load4(const float* p){ return *(const f32x4*)p; }

// A-fragment for 16x16x32 (A[m=lane&15][k=(lane>>4)*8+j]), scaled on load.
__device__ __forceinline__ f16x8 afrag_s(const float* p, float s){
    float4 a = *(const float4*)p, b = *(const float4*)(p+4);
    f16x8 r;
    r[0]=(_Float16)(a.x*s); r[1]=(_Float16)(a.y*s); r[2]=(_Float16)(a.z*s); r[3]=(_Float16)(a.w*s);
    r[4]=(_Float16)(b.x*s); r[5]=(_Float16)(b.y*s); r[6]=(_Float16)(b.z*s); r[7]=(_Float16)(b.w*s);
    return r;
}

// tanh with z = SCALE*u pre-folded: e = 2^z = e^{2u}; tanh = 1 - 2/(1+e).
__device__ __forceinline__ float tanh_pre(float z){
#if __has_builtin(__builtin_amdgcn_exp2f)
    float e = __builtin_amdgcn_exp2f(z);
#else
    float e = exp2f(z);
#endif
    return __builtin_fmaf(-2.f, __builtin_amdgcn_rcpf(1.f + e), 1.f);
}

__device__ __forceinline__ unsigned pk2(float a, float b){
    union { pk16x2 h; unsigned u; } c;
    c.h = __builtin_amdgcn_cvt_pkrtz(a, b);
    return c.u;
}

// pack 8 f32 (two float4) into an f16x8 B-fragment (RTZ, same as h path).
__device__ __forceinline__ f16x8 xfrag(float4 a, float4 b){
    union { unsigned u[4]; f16x8 v; } c;
    c.u[0] = pk2(a.x, a.y); c.u[1] = pk2(a.z, a.w);
    c.u[2] = pk2(b.x, b.y); c.u[3] = pk2(b.z, b.w);
    return c.v;
}

// ---------------------------------------------------------------------------
// scan v7 = v6 (8 waves, proj+fill fused) with:
//   (1) 272B row stride -> all state reads are single ds_read_b128
//       (2-way bank aliasing, measured-free on this chip; halves LDS op count);
//   (2) split dependent MFMA accumulation chains (L1 6-deep -> 2x3; L2 z/y
//       4-deep -> 2x2 each; FC 4 -> 2+2);
//   (3) s_setprio(1) around the heavy (L2) MFMA cluster.
// ---------------------------------------------------------------------------
#define LSTR2 136               // halves per row; 272 B row stride (16B-aligned frags)
#define PHB   (NB*LSTR2*2)      // bytes per phase = 4352

#define STEP_L1(T_, P_, XS_) do {                                             \
    const int t_ = (T_);                                                      \
    f16x8 bh1[4];                                                             \
    _Pragma("unroll")                                                         \
    for (int kt = 0; kt < 4; ++kt)                                            \
        bh1[kt] = *(const f16x8*)(h1b + (P_)*PHB + kt*64);                    \
    const bool doZ0 = (t_ < maxlen);                                          \
    f32x4 za[2], zb[2];                                                       \
    if (doZ0){                                                                \
        f16x8 xB0 = xfrag(XS_[0], XS_[1]);                                    \
        f16x8 xB1 = xfrag(XS_[2], XS_[3]);                                    \
        _Pragma("unroll")                                                     \
        for (int m = 0; m < 2; ++m){                                          \
            za[m] = bv0[m];                                                   \
            za[m] = MFMA16(Aih[m][0], xB0, za[m]);                            \
            zb[m][0]=0.f; zb[m][1]=0.f; zb[m][2]=0.f; zb[m][3]=0.f;           \
            zb[m] = MFMA16(Aih[m][1], xB1, zb[m]);                            \
        }                                                                     \
        _Pragma("unroll")                                                     \
        for (int m = 0; m < 2; ++m){                                          \
            za[m] = MFMA16(A0[m][0], bh1[0], za[m]);                          \
            zb[m] = MFMA16(A0[m][1], bh1[1], zb[m]);                          \
            za[m] = MFMA16(A0[m][2], bh1[2], za[m]);                          \
            zb[m] = MFMA16(A0[m][3], bh1[3], zb[m]);                          \
        }                                                                     \
    }                                                                         \
    {   /* unconditional clamped x reload into the SAME named slots */        \
        const int tl = (t_ + 2 < TT) ? (t_ + 2) : (TT - 1);                   \
        const float* xq = xb + (size_t)tl*DD;                                 \
        XS_[0] = *(const float4*)(xq);                                        \
        XS_[1] = *(const float4*)(xq + 4);                                    \
        XS_[2] = *(const float4*)(xq + 32);                                   \
        XS_[3] = *(const float4*)(xq + 36);                                   \
    }                                                                         \
    if (doZ0){                                                                \
        _Pragma("unroll")                                                     \
        for (int m = 0; m < 2; ++m){                                          \
            f32x4 zz = za[m] + zb[m];                                         \
            uint2 v;                                                          \
            v.x = pk2(tanh_pre(zz[0]), tanh_pre(zz[1]));                      \
            v.y = pk2(tanh_pre(zz[2]), tanh_pre(zz[3]));                      \
            *(uint2*)((char*)H1T + ((P_)^1)*PHB + n*272 + (w*2+m)*32 + q*8) = v; \
        }                                                                     \
    }                                                                         \
    asm volatile("s_waitcnt lgkmcnt(0)\n\ts_barrier" ::: "memory");           \
} while (0)

#define STEP_L2(T_, P_) do {                                                  \
    const int t_ = (T_);                                                      \
    f16x8 bh1[4], bh2[4];                                                     \
    _Pragma("unroll")                                                         \
    for (int kt = 0; kt < 4; ++kt){                                           \
        bh1[kt] = *(const f16x8*)(h1b + (P_)*PHB + kt*64);                    \
        bh2[kt] = *(const f16x8*)(h2b + (P_)*PHB + kt*64);                    \
    }                                                                         \
    const bool doZ1 = (t_ >= 1) && (t_ <= maxlen);                            \
    f32x4 za[2], zb[2], ya[2], yb[2];                                         \
    __builtin_amdgcn_s_setprio(1);                                            \
    if (doZ1){                                                                \
        _Pragma("unroll")                                                     \
        for (int m = 0; m < 2; ++m){                                          \
            za[m] = b1v[m];                                                   \
            zb[m][0]=0.f; zb[m][1]=0.f; zb[m][2]=0.f; zb[m][3]=0.f;           \
            ya[m] = zb[m]; yb[m] = zb[m];                                     \
        }                                                                     \
        _Pragma("unroll")                                                     \
        for (int m = 0; m < 2; ++m){                                          \
            za[m] = MFMA16(Ai[m][0], bh1[0], za[m]);                          \
            zb[m] = MFMA16(Ai[m][1], bh1[1], zb[m]);                          \
            ya[m] = MFMA16(Ah[m][0], bh2[0], ya[m]);                          \
            yb[m] = MFMA16(Ah[m][1], bh2[1], yb[m]);                          \
            za[m] = MFMA16(Ai[m][2], bh1[2], za[m]);                          \
            zb[m] = MFMA16(Ai[m][3], bh1[3], zb[m]);                          \
            ya[m] = MFMA16(Ah[m][2], bh2[2], ya[m]);                          \
            yb[m] = MFMA16(Ah[m][3], bh2[3], yb[m]);                          \
        }                                                                     \
    }                                                                         \
    if (doFC && t_ >= 2){                                                     \
        f32x4 zfa = bfv, zfb;                                                 \
        zfb[0]=0.f; zfb[1]=0.f; zfb[2]=0.f; zfb[3]=0.f;                       \
        zfa = MFMA16(Af[0], bh2[0], zfa);                                     \
        zfb = MFMA16(Af[1], bh2[1], zfb);                                     \
        zfa = MFMA16(Af[2], bh2[2], zfa);                                     \
        zfb = MFMA16(Af[3], bh2[3], zfb);                                     \
        if (t_ - 2 < lenn){                                                   \
            f32x4 zf = zfa + zfb;                                             \
            float4 sv; sv.x=zf[0]; sv.y=zf[1]; sv.z=zf[2]; sv.w=zf[3];        \
            *(float4*)(obase + (size_t)(t_-2)*OO) = sv;                       \
        }                                                                     \
    }                                                                         \
    __builtin_amdgcn_s_setprio(0);                                            \
    if (doZ1){                                                                \
        _Pragma("unroll")                                                     \
        for (int m = 0; m < 2; ++m){                                          \
            f32x4 zz = (za[m] + zb[m]) + (ya[m] + yb[m]);                     \
            uint2 v;                                                          \
            v.x = pk2(tanh_pre(zz[0]), tanh_pre(zz[1]));                      \
            v.y = pk2(tanh_pre(zz[2]), tanh_pre(zz[3]));                      \
            *(uint2*)((char*)H2T + ((P_)^1)*PHB + n*272 + (wl*2+m)*32 + q*8) = v; \
        }                                                                     \
    }                                                                         \
    asm volatile("s_waitcnt lgkmcnt(0)\n\ts_barrier" ::: "memory");           \
} while (0)

extern "C" __global__ void __launch_bounds__(512, 1)
scan_kernel(const float* __restrict__ x, const int* __restrict__ lengths,
            const float* __restrict__ W_ih0, const float* __restrict__ W_hh0,
            const float* __restrict__ b_ih0, const float* __restrict__ b_hh0,
            const float* __restrict__ W_ih1, const float* __restrict__ W_hh1,
            const float* __restrict__ b_ih1, const float* __restrict__ b_hh1,
            const float* __restrict__ W_fc,  const float* __restrict__ b_fc,
            float* __restrict__ out)
{
    const int tid  = threadIdx.x;
    const int w    = tid >> 6, lane = tid & 63;
    const int n    = lane & 15, q = lane >> 4;
    const int rbase= blockIdx.x * NB;

    __shared__ __align__(16) _Float16 H1T[2][NB][LSTR2];
    __shared__ __align__(16) _Float16 H2T[2][NB][LSTR2];

    for (int idx = tid; idx < (2*NB*LSTR2)/2; idx += 512){
        ((unsigned*)H1T)[idx] = 0u;
        ((unsigned*)H2T)[idx] = 0u;
    }

    const int lenn = lengths[rbase + n];
    int mx = lenn;
    #pragma unroll
    for (int s = 1; s < 16; s <<= 1){ int o = __shfl_xor(mx, s, 64); mx = max(mx, o); }
    const int maxlen = __builtin_amdgcn_readfirstlane(mx);

    const char* h1b = (const char*)H1T + n*272 + q*16;
    const char* h2b = (const char*)H2T + n*272 + q*16;

    __syncthreads();

    if (w < 4){
        // ---- L1 waves: m-tiles {2w, 2w+1}; proj fused inline ----
        f16x8 A0[2][4], Aih[2][2];
        f32x4 bv0[2];
        #pragma unroll
        for (int m = 0; m < 2; ++m){
            const int row = (w*2 + m)*16 + n;
            #pragma unroll
            for (int kt = 0; kt < 4; ++kt)
                A0[m][kt] = afrag_s(W_hh0 + row*HH + kt*32 + q*8, SCALE);
            #pragma unroll
            for (int kt = 0; kt < 2; ++kt)
                Aih[m][kt] = afrag_s(W_ih0 + row*DD + kt*32 + q*8, SCALE);
            bv0[m] = (load4(b_ih0 + (w*2+m)*16 + q*4)
                    + load4(b_hh0 + (w*2+m)*16 + q*4)) * SCALE;
        }

        const float* xb = x + ((size_t)(rbase+n)*TT)*DD + q*8;

        float4 xe[4], xo[4];
        {
            const float* x0 = xb;
            const float* x1 = xb + DD;
            xe[0] = *(const float4*)(x0);      xe[1] = *(const float4*)(x0 + 4);
            xe[2] = *(const float4*)(x0 + 32); xe[3] = *(const float4*)(x0 + 36);
            xo[0] = *(const float4*)(x1);      xo[1] = *(const float4*)(x1 + 4);
            xo[2] = *(const float4*)(x1 + 32); xo[3] = *(const float4*)(x1 + 36);
        }

        for (int t0 = 0; t0 <= maxlen + 1; t0 += 2){
            STEP_L1(t0,     0, xe);
            STEP_L1(t0 + 1, 1, xo);
        }
    } else {
        // ---- L2 waves: m-tiles {2wl, 2wl+1}; waves 4,5 add FC half wl ----
        const int wl = w - 4;
        const bool doFC = (wl < 2);
        const int f = wl & 1;
        f16x8 Ai[2][4], Ah[2][4];
        f32x4 b1v[2];
        #pragma unroll
        for (int m = 0; m < 2; ++m){
            const int row = (wl*2 + m)*16 + n;
            #pragma unroll
            for (int kt = 0; kt < 4; ++kt){
                Ai[m][kt] = afrag_s(W_ih1 + row*HH + kt*32 + q*8, SCALE);
                Ah[m][kt] = afrag_s(W_hh1 + row*HH + kt*32 + q*8, SCALE);
            }
            b1v[m] = (load4(b_ih1 + (wl*2+m)*16 + q*4)
                    + load4(b_hh1 + (wl*2+m)*16 + q*4)) * SCALE;
        }
        f16x8 Af[4];
        #pragma unroll
        for (int kt = 0; kt < 4; ++kt)
            Af[kt] = afrag_s(W_fc + (f*16 + n)*HH + kt*32 + q*8, 1.0f);
        const f32x4 bfv = load4(b_fc + f*16 + q*4);

        float* obase = out + ((size_t)(rbase+n)*TT)*OO + f*16 + q*4;

        for (int t0 = 0; t0 <= maxlen + 1; t0 += 2){
            STEP_L2(t0,     0);
            STEP_L2(t0 + 1, 1);
        }
    }

    // ---- fused pad-fill tail: out[b][t][:] = b_fc for t >= lengths[b] ----
    {
        const int row  = tid >> 5;             // 0..15
        const int lr   = lengths[rbase + row];
        const int o4   = tid & 7;              // float4 index within 32 floats
        const int tpar = (tid >> 3) & 3;       // t offset (stride 4)
        const float4 bf4 = *(const float4*)(b_fc + o4*4);
        float* ob = out + ((size_t)(rbase+row)*TT)*OO + o4*4;
        for (int t = lr + tpar; t < TT; t += 4)
            *(float4*)(ob + (size_t)t*OO) = bf4;
    }
}

// ---------------------------------------------------------------------------
extern "C" void kernel_launch(void* const* d_in, const int* in_sizes, int n_in,
                              void* d_out, int out_size, void* d_ws, size_t ws_size,
                              hipStream_t stream)
{
    const float* x       = (const float*)d_in[0];
    const int*   lengths = (const int*)  d_in[1];
    const float* W_ih0   = (const float*)d_in[2];
    const float* W_hh0   = (const float*)d_in[3];
    const float* b_ih0   = (const float*)d_in[4];
    const float* b_hh0   = (const float*)d_in[5];
    const float* W_ih1   = (const float*)d_in[6];
    const float* W_hh1   = (const float*)d_in[7];
    const float* b_ih1   = (const float*)d_in[8];
    const float* b_hh1   = (const float*)d_in[9];
    const float* W_fc    = (const float*)d_in[10];
    const float* b_fc    = (const float*)d_in[11];

    scan_kernel<<<BB/NB, 512, 0, stream>>>(x, lengths, W_ih0, W_hh0,
                                           b_ih0, b_hh0,
                                           W_ih1, W_hh1, b_ih1, b_hh1,
                                           W_fc, b_fc, (float*)d_out);
}